// Round 1
// baseline (158.555 us; speedup 1.0000x reference)
//
#include <hip/hip_runtime.h>
#include <hip/hip_bf16.h>

typedef short bf16x8 __attribute__((ext_vector_type(8)));
typedef float f32x4 __attribute__((ext_vector_type(4)));

#define D_DIM   128
#define S_LEN   16384
#define N_ROWS  (16 * 16384)       // B*S = 262144 frames
#define NBLOCKS 512
#define NTILES  (N_ROWS / 64)      // 64 rows per block-tile (16 per wave) -> 4096

__device__ __forceinline__ unsigned short f2bf(float f) {
    // round-to-nearest-even fp32 -> bf16 (inputs are finite; no NaN handling needed)
    unsigned u = __builtin_bit_cast(unsigned, f);
    unsigned r = (u + 0x7fffu + ((u >> 16) & 1u)) >> 16;
    return (unsigned short)r;
}

__launch_bounds__(256, 2)
__global__ void ssm_fused_kernel(const float* __restrict__ x,
                                 const int*   __restrict__ mask,
                                 const float* __restrict__ W1,
                                 const float* __restrict__ b1,
                                 const float* __restrict__ W2,
                                 const float* __restrict__ b2,
                                 float* __restrict__ out) {
    // LDS: W1^T, W2^T in bf16 (swizzled), per-wave h buffer. 32+32+16 = 80 KiB -> 2 blocks/CU.
    __shared__ __align__(16) unsigned short w1t[128 * 128];
    __shared__ __align__(16) unsigned short w2t[128 * 128];
    __shared__ __align__(16) unsigned short hlds[4 * 16 * 128];

    const int tid  = threadIdx.x;
    const int lane = tid & 63;
    const int wv   = tid >> 6;   // wave 0..3
    const int ln   = lane & 15;  // MFMA row/col index within 16
    const int g    = lane >> 4;  // MFMA k-group 0..3

    // ---- stage W1^T, W2^T (bf16, XOR-swizzled units) once per block ----
    // element (n=col of W, k=row of W): u16 idx = n*128 + ((k>>3)^(n&15))*8 + (k&7)
    for (int i = tid; i < 4096; i += 256) {
        int k  = i >> 5;          // W row 0..127
        int n0 = (i & 31) * 4;    // W col
        float4 v1 = *(const float4*)(W1 + k * 128 + n0);
        float4 v2 = *(const float4*)(W2 + k * 128 + n0);
        const float* p1 = (const float*)&v1;
        const float* p2 = (const float*)&v2;
#pragma unroll
        for (int j = 0; j < 4; ++j) {
            int n   = n0 + j;
            int idx = n * 128 + ((((k >> 3) ^ (n & 15))) << 3) + (k & 7);
            w1t[idx] = f2bf(p1[j]);
            w2t[idx] = f2bf(p2[j]);
        }
    }
    __syncthreads();

    // per-lane bias fragments (col = ct*16 + ln)
    float b1f[8], b2f[8];
#pragma unroll
    for (int ct = 0; ct < 8; ++ct) {
        b1f[ct] = b1[ct * 16 + ln];
        b2f[ct] = b2[ct * 16 + ln];
    }

    unsigned short* hw = hlds + wv * (16 * 128);
    const f32x4 zero = {0.0f, 0.0f, 0.0f, 0.0f};

    for (int tile = blockIdx.x; tile < NTILES; tile += NBLOCKS) {
        const int row0  = tile * 64 + wv * 16;   // this wave's first row
        const int myrow = row0 + ln;
        const float* xp = x + (long)myrow * D_DIM + g * 8;

        // ---- load x A-fragments: lane holds X[myrow][kc*32 + g*8 .. +8] ----
        bf16x8 a[4];
#pragma unroll
        for (int kc = 0; kc < 4; ++kc) {
            float4 lo = *(const float4*)(xp + kc * 32);
            float4 hi = *(const float4*)(xp + kc * 32 + 4);
            bf16x8 t;
            t[0] = f2bf(lo.x); t[1] = f2bf(lo.y); t[2] = f2bf(lo.z); t[3] = f2bf(lo.w);
            t[4] = f2bf(hi.x); t[5] = f2bf(hi.y); t[6] = f2bf(hi.z); t[7] = f2bf(hi.w);
            a[kc] = t;
        }

        // ---- layer 1: H = X @ W1 ----
        f32x4 acc1[8];
#pragma unroll
        for (int ct = 0; ct < 8; ++ct) acc1[ct] = zero;
#pragma unroll
        for (int kc = 0; kc < 4; ++kc) {
#pragma unroll
            for (int ct = 0; ct < 8; ++ct) {
                // B-frag: W1[kc*32+g*8+j][ct*16+ln] = W1T[ct*16+ln][k...]
                const bf16x8 bfrag = *(const bf16x8*)&w1t[(ct * 16 + ln) * 128 + (((kc * 4 + g) ^ ln) << 3)];
                acc1[ct] = __builtin_amdgcn_mfma_f32_16x16x32_bf16(a[kc], bfrag, acc1[ct], 0, 0, 0);
            }
        }

        // ---- bias + silu, write h to per-wave LDS (swizzled) ----
        // acc layout: row=(g*4+r), col=ct*16+ln  [verified C/D mapping]
#pragma unroll
        for (int ct = 0; ct < 8; ++ct) {
#pragma unroll
            for (int r = 0; r < 4; ++r) {
                float z    = acc1[ct][r] + b1f[ct];
                float hval = z / (1.0f + __expf(-z));
                int row = g * 4 + r;
                int c   = ct * 16 + ln;
                hw[row * 128 + ((((c >> 3) ^ row)) << 3) + (c & 7)] = f2bf(hval);
            }
        }

        // ---- read h A-fragments (same-wave LDS round trip; no barrier needed) ----
        bf16x8 ha[4];
#pragma unroll
        for (int kc = 0; kc < 4; ++kc)
            ha[kc] = *(const bf16x8*)&hw[ln * 128 + (((kc * 4 + g) ^ ln) << 3)];

        // ---- layer 2: Y = H @ W2 ----
        f32x4 acc2[8];
#pragma unroll
        for (int ct = 0; ct < 8; ++ct) acc2[ct] = zero;
#pragma unroll
        for (int kc = 0; kc < 4; ++kc) {
#pragma unroll
            for (int ct = 0; ct < 8; ++ct) {
                const bf16x8 bfrag = *(const bf16x8*)&w2t[(ct * 16 + ln) * 128 + (((kc * 4 + g) ^ ln) << 3)];
                acc2[ct] = __builtin_amdgcn_mfma_f32_16x16x32_bf16(ha[kc], bfrag, acc2[ct], 0, 0, 0);
            }
        }

        // ---- epilogue: bias + mask + hard-reset decay, store ----
        float fac[4];
#pragma unroll
        for (int r = 0; r < 4; ++r) {
            int n = row0 + g * 4 + r;
            unsigned s = (unsigned)(n & (S_LEN - 1));
            float sc = (((s + 1u) % 10u) == 0u) ? 0.1f : 1.0f;
            fac[r] = mask[n] ? sc : 0.0f;
        }
#pragma unroll
        for (int ct = 0; ct < 8; ++ct) {
#pragma unroll
            for (int r = 0; r < 4; ++r) {
                int n = row0 + g * 4 + r;
                out[(long)n * D_DIM + ct * 16 + ln] = (acc2[ct][r] + b2f[ct]) * fac[r];
            }
        }
    }
}

extern "C" void kernel_launch(void* const* d_in, const int* in_sizes, int n_in,
                              void* d_out, int out_size, void* d_ws, size_t ws_size,
                              hipStream_t stream) {
    const float* x    = (const float*)d_in[0];
    const int*   mask = (const int*)d_in[1];
    const float* W1   = (const float*)d_in[2];
    const float* b1   = (const float*)d_in[3];
    const float* W2   = (const float*)d_in[4];
    const float* b2   = (const float*)d_in[5];
    float* out = (float*)d_out;

    hipLaunchKernelGGL(ssm_fused_kernel, dim3(NBLOCKS), dim3(256), 0, stream,
                       x, mask, W1, b1, W2, b2, out);
}